// Round 3
// baseline (847.882 us; speedup 1.0000x reference)
//
#include <hip/hip_runtime.h>
#include <math.h>

// MoE gate: logits = x @ W^T + bias ; softmax ; top-8 ; dense scatter.
// x: 16384 x 2048 f32, W: 64 x 2048 f32, bias: 64 f32 (zeros).
// Outputs concatenated in d_out (float32): vals[16384*8] | idx[16384*8] | dense[16384*64].
//
// Accuracy strategy (r3): bit-replicate numpy's C einsum inner loop
// (sum_of_products_contig_contig_outstride0_two, npyv baseline SSE2/SSE3,
// no FMA, 4 lanes):
//   - 4 partial sums, lane j takes elements k ≡ j (mod 4)
//   - blocks of 16 elements ascending; within a block products are added in
//     REVERSE vector order (offsets 12..15 first, then 8.., 4.., 0..)
//   - every mul and add separately rounded f32 (fp contract OFF)
//   - final reduce = SSE3 hadd tree: (L0+L1) + (L2+L3)
// Top-8 ranked by these f32 logits (softmax monotone; ties -> lowest index,
// matching stable top_k). r1 (sequential fmaf) and r2 (exact f64) each lost
// ~1 near-tie ordering race vs this chain.

#define NROWS 16384
#define DIM 2048
#define NE 64
#define DC 128            // K-tile (floats)
#define NTILES (DIM / DC) // 16

__device__ __forceinline__ void ld16_lds(const float* g, void* l) {
  __builtin_amdgcn_global_load_lds((const __attribute__((address_space(1))) void*)g,
                                   (__attribute__((address_space(3))) void*)l, 16, 0, 0);
}

__global__ __launch_bounds__(512, 2)
void gate_kernel(const float* __restrict__ x, const float* __restrict__ w,
                 const float* __restrict__ bias, float* __restrict__ out_vals,
                 float* __restrict__ out_idx, float* __restrict__ out_dense)
{
  // Two 32 KB x-tiles: [64 rows][32 float4], XOR-swizzled slots.
  __shared__ float4 xs[2][64 * 32];
  __shared__ unsigned long long msk[64];

  const int t    = threadIdx.x;
  const int wv   = t >> 6;     // wave 0..7 -> expert octet
  const int lane = t & 63;     // row within block
  const int rowBase = blockIdx.x << 6;
  const int e0 = wv << 3;

  // ---- stage one K-tile into LDS buffer `buf` ----
  // Linear LDS dest (global_load_lds writes base + lane*16); XOR swizzle is
  // applied on the GLOBAL source address (both-sides-or-neither rule).
  auto stage = [&](int buf, int kt) {
    const int d0 = kt * DC;
#pragma unroll
    for (int it = 0; it < 4; ++it) {
      int q   = it * 512 + t;      // linear float4 index in tile
      int row = q >> 5;            // 32 slots per row
      int sp  = q & 31;            // LDS slot
      int ss  = sp ^ (row & 7);    // source slot (XOR is an involution)
      const float* g = x + (size_t)(rowBase + row) * DIM + d0 + (ss << 2);
      ld16_lds(g, &xs[buf][q]);
    }
  };

  // acc[e] = 4-lane partial sums (np einsum SIMD accumulator)
  float4 acc[8];
#pragma unroll
  for (int e = 0; e < 8; ++e) acc[e] = make_float4(0.f, 0.f, 0.f, 0.f);

  auto compute = [&](int buf, int kt) {
#pragma clang fp contract(off)
    const int d0 = kt * DC;
    const float4* xr = &xs[buf][lane << 5];
    const int sw = lane & 7;
#pragma unroll
    for (int b = 0; b < 8; ++b) {          // 16-element blocks, ascending
      float4 q0 = xr[(4 * b + 0) ^ sw];
      float4 q1 = xr[(4 * b + 1) ^ sw];
      float4 q2 = xr[(4 * b + 2) ^ sw];
      float4 q3 = xr[(4 * b + 3) ^ sw];
      const float* wp = w + d0 + (b << 4);
#pragma unroll
      for (int e = 0; e < 8; ++e) {
        const float* we = wp + (size_t)(e0 + e) * DIM;
        float4 r0 = *(const float4*)(we);
        float4 r1 = *(const float4*)(we + 4);
        float4 r2 = *(const float4*)(we + 8);
        float4 r3 = *(const float4*)(we + 12);
        // np chain: vacc += a3*b3, then a2*b2, a1*b1, a0*b0 (mul/add unfused)
        acc[e].x = acc[e].x + q3.x * r3.x;
        acc[e].y = acc[e].y + q3.y * r3.y;
        acc[e].z = acc[e].z + q3.z * r3.z;
        acc[e].w = acc[e].w + q3.w * r3.w;
        acc[e].x = acc[e].x + q2.x * r2.x;
        acc[e].y = acc[e].y + q2.y * r2.y;
        acc[e].z = acc[e].z + q2.z * r2.z;
        acc[e].w = acc[e].w + q2.w * r2.w;
        acc[e].x = acc[e].x + q1.x * r1.x;
        acc[e].y = acc[e].y + q1.y * r1.y;
        acc[e].z = acc[e].z + q1.z * r1.z;
        acc[e].w = acc[e].w + q1.w * r1.w;
        acc[e].x = acc[e].x + q0.x * r0.x;
        acc[e].y = acc[e].y + q0.y * r0.y;
        acc[e].z = acc[e].z + q0.z * r0.z;
        acc[e].w = acc[e].w + q0.w * r0.w;
      }
    }
  };

  // ---- double-buffered main loop: counted vmcnt, raw barriers ----
  stage(0, 0);
#pragma unroll 1
  for (int kt = 0; kt < NTILES - 1; ++kt) {
    stage((kt + 1) & 1, kt + 1);                       // prefetch next tile
    asm volatile("s_waitcnt vmcnt(4)" ::: "memory");   // cur tile's 4 loads done
    __builtin_amdgcn_s_barrier();
    compute(kt & 1, kt);
    __builtin_amdgcn_s_barrier();                      // readers done before overwrite
    asm volatile("" ::: "memory");
  }
  asm volatile("s_waitcnt vmcnt(0)" ::: "memory");
  __builtin_amdgcn_s_barrier();
  compute((NTILES - 1) & 1, NTILES - 1);

  __syncthreads();   // everyone done with xs before overlaying logits

  // ---- f32 logits to LDS overlay: lg[64][65] | pr[64][65] ----
  float* lg = (float*)&xs[0][0];
  float* pr = lg + 64 * 65;
  {
#pragma clang fp contract(off)
#pragma unroll
    for (int e = 0; e < 8; ++e) {
      float s01 = acc[e].x + acc[e].y;   // SSE3 hadd tree
      float s23 = acc[e].z + acc[e].w;
      float l   = s01 + s23;
      lg[lane * 65 + e0 + e] = l + bias[e0 + e];  // bias = 0, no-op
    }
  }
  __syncthreads();

  // ---- softmax (np-style) + top-8 ranked by f32 logits (wave 0) ----
  if (t < 64) {
#pragma clang fp contract(off)
    const int r = t;
    const float* lgr = lg + (size_t)r * 65;
    float* prr = pr + (size_t)r * 65;
    float m = lgr[0];
    for (int e = 1; e < NE; ++e) m = fmaxf(m, lgr[e]);
    for (int e = 0; e < NE; ++e) prr[e] = expf(lgr[e] - m);
    // np pairwise sum, n=64: 8 accumulators + tree
    float rs[8];
    for (int j = 0; j < 8; ++j) rs[j] = prr[j];
    for (int i = 8; i < NE; i += 8)
      for (int j = 0; j < 8; ++j) rs[j] = rs[j] + prr[i + j];
    float s = ((rs[0] + rs[1]) + (rs[2] + rs[3])) + ((rs[4] + rs[5]) + (rs[6] + rs[7]));
    for (int e = 0; e < NE; ++e) prr[e] = prr[e] / s;

    unsigned long long used = 0;
    const int grow = rowBase + r;
    for (int k = 0; k < 8; ++k) {
      float best = -INFINITY; int bi = -1;
      for (int e = 0; e < NE; ++e) {
        if ((used >> e) & 1ull) continue;
        float v = lgr[e];
        if (v > best) { best = v; bi = e; }   // strict >: lowest index wins ties
      }
      used |= 1ull << bi;
      out_vals[(size_t)grow * 8 + k] = prr[bi];
      out_idx [(size_t)grow * 8 + k] = (float)bi;
    }
    msk[r] = used;
  }
  __syncthreads();

  // ---- dense gate: cooperative coalesced write of 64x64 tile ----
  for (int i = t; i < 64 * NE; i += 512) {
    int r = i >> 6, e = i & 63;
    float v = ((msk[r] >> e) & 1ull) ? pr[(size_t)r * 65 + e] : 0.0f;
    out_dense[(size_t)(rowBase + r) * NE + e] = v;
  }
}

extern "C" void kernel_launch(void* const* d_in, const int* in_sizes, int n_in,
                              void* d_out, int out_size, void* d_ws, size_t ws_size,
                              hipStream_t stream) {
  const float* x    = (const float*)d_in[0];
  const float* w    = (const float*)d_in[1];
  const float* bias = (const float*)d_in[2];
  float* out   = (float*)d_out;
  float* vals  = out;                       // 16384*8
  float* idx   = out + (size_t)NROWS * 8;   // 16384*8
  float* dense = out + (size_t)NROWS * 16;  // 16384*64
  (void)in_sizes; (void)n_in; (void)out_size; (void)d_ws; (void)ws_size;
  gate_kernel<<<dim3(NROWS / 64), dim3(512), 0, stream>>>(x, w, bias, vals, idx, dense);
}

// Round 5
// 373.015 us; speedup vs baseline: 2.2730x; 2.2730x over previous
//
#include <hip/hip_runtime.h>
#include <math.h>

// Unfused mul/add EVERYWHERE (file scope): the exact-chain replication of
// numpy's einsum requires separately-rounded mul and add; address math and
// staging are unaffected by contract(off).
#pragma clang fp contract(off)

// MoE gate: logits = x @ W^T + bias ; softmax ; top-8 ; dense scatter.
// Outputs (float32): vals[16384*8] | idx[16384*8] | dense[16384*64].
//
// PASSED math (r3) — DO NOT CHANGE: logits replicate numpy's einsum inner loop
// (npyv SSE2/SSE3, no FMA): 4 partial lanes (k mod 4), 16-element blocks
// ascending, REVERSE vector order within block, every mul/add separately
// rounded, final SSE3 hadd tree (L0+L1)+(L2+L3). Top-8 ranked by these exact
// f32 logits, strict >, lowest index on tie; softmax = exp(l-max), np
// pairwise-8 sum, IEEE div.
//
// r5 structure (= r4 + pragma fix): two kernels. A: logits -> dense region of
// d_out (scratch, overwritten by B). 1024 blocks x 256 thr (64 rows x 16
// experts), 4 blk/CU, W via wave-uniform scalar loads (readfirstlane), x
// staged global_load_lds + XOR swizzle. B: per-row softmax/top8/scatter.

#define NROWS 16384
#define DIM   2048
#define NE    64
#define DC    64
#define NTILES (DIM / DC)   // 32

__device__ __forceinline__ void ld16_lds(const float* g, void* l) {
  __builtin_amdgcn_global_load_lds((const __attribute__((address_space(1))) void*)g,
                                   (__attribute__((address_space(3))) void*)l, 16, 0, 0);
}

// np 16-element block, reverse order, unfused mul/add.
#define NP_BLOCK(A, Q0, Q1, Q2, Q3, R0, R1, R2, R3) \
  A.x = A.x + Q3.x * R3.x;  A.y = A.y + Q3.y * R3.y; \
  A.z = A.z + Q3.z * R3.z;  A.w = A.w + Q3.w * R3.w; \
  A.x = A.x + Q2.x * R2.x;  A.y = A.y + Q2.y * R2.y; \
  A.z = A.z + Q2.z * R2.z;  A.w = A.w + Q2.w * R2.w; \
  A.x = A.x + Q1.x * R1.x;  A.y = A.y + Q1.y * R1.y; \
  A.z = A.z + Q1.z * R1.z;  A.w = A.w + Q1.w * R1.w; \
  A.x = A.x + Q0.x * R0.x;  A.y = A.y + Q0.y * R0.y; \
  A.z = A.z + Q0.z * R0.z;  A.w = A.w + Q0.w * R0.w;

__global__ __launch_bounds__(256, 4)
void logits_kernel(const float* __restrict__ x, const float* __restrict__ w,
                   const float* __restrict__ bias, float* __restrict__ lg)
{
  __shared__ float4 xs[2][64 * (DC / 4)];   // 2 x 16 KB

  const int t    = threadIdx.x;
  const int wv   = t >> 6;      // 0..3 -> expert quad within group
  const int lane = t & 63;      // row within tile
  // XCD decode: 4 sibling blocks (same 64 rows, expert groups 0..3) share an
  // XCD so the x-tile is fetched once per XCD L2 (default assignment = bid&7).
  const int bid = blockIdx.x;          // 0..1023
  const int ix  = bid >> 3;            // 0..127
  const int qg  = ix & 3;              // expert group
  const int rg  = (bid & 7) + ((ix >> 2) << 3);  // row group 0..255 (bijective)
  const int rowBase = rg << 6;
  const int e_base  = __builtin_amdgcn_readfirstlane((qg << 4) | (wv << 2));
  const float* wb = w + (size_t)e_base * DIM;   // wave-uniform -> s_load path

  auto stage = [&](int buf, int kt) {
    const int d0 = kt * DC;
#pragma unroll
    for (int it = 0; it < 4; ++it) {
      int q   = (it << 8) + t;     // float4 index in [64][16] tile
      int row = q >> 4;
      int sp  = q & 15;
      int ss  = sp ^ (row & 7);    // swizzle on the GLOBAL source (involution)
      const float* g = x + (size_t)(rowBase + row) * DIM + d0 + (ss << 2);
      ld16_lds(g, &xs[buf][q]);
    }
  };

  float4 acc[4];
#pragma unroll
  for (int e = 0; e < 4; ++e) acc[e] = make_float4(0.f, 0.f, 0.f, 0.f);

  auto compute = [&](int buf, int kt) {
    const int d0 = kt * DC;
    const float4* xr = &xs[buf][lane << 4];
    const int sw = lane & 7;
#pragma unroll
    for (int b = 0; b < 4; ++b) {        // np 16-blocks, ascending
      float4 q0 = xr[(4 * b + 0) ^ sw];
      float4 q1 = xr[(4 * b + 1) ^ sw];
      float4 q2 = xr[(4 * b + 2) ^ sw];
      float4 q3 = xr[(4 * b + 3) ^ sw];
      const float* wp = wb + d0 + (b << 4);
#pragma unroll
      for (int e = 0; e < 4; ++e) {
        const float* we = wp + (size_t)e * DIM;  // uniform -> SGPR loads
        float4 r0 = *(const float4*)(we);
        float4 r1 = *(const float4*)(we + 4);
        float4 r2 = *(const float4*)(we + 8);
        float4 r3 = *(const float4*)(we + 12);
        NP_BLOCK(acc[e], q0, q1, q2, q3, r0, r1, r2, r3)
      }
    }
  };

  stage(0, 0);
#pragma unroll 1
  for (int kt = 0; kt < NTILES - 1; ++kt) {
    stage((kt + 1) & 1, kt + 1);                       // prefetch next tile
    asm volatile("s_waitcnt vmcnt(4)" ::: "memory");   // cur tile staged
    __builtin_amdgcn_s_barrier();
    compute(kt & 1, kt);
    __builtin_amdgcn_s_barrier();                      // readers done
    asm volatile("" ::: "memory");
  }
  asm volatile("s_waitcnt vmcnt(0)" ::: "memory");
  __builtin_amdgcn_s_barrier();
  compute((NTILES - 1) & 1, NTILES - 1);

  {
    float4 res;
    float s01, s23;
    s01 = acc[0].x + acc[0].y; s23 = acc[0].z + acc[0].w;
    res.x = (s01 + s23) + bias[e_base + 0];
    s01 = acc[1].x + acc[1].y; s23 = acc[1].z + acc[1].w;
    res.y = (s01 + s23) + bias[e_base + 1];
    s01 = acc[2].x + acc[2].y; s23 = acc[2].z + acc[2].w;
    res.z = (s01 + s23) + bias[e_base + 2];
    s01 = acc[3].x + acc[3].y; s23 = acc[3].z + acc[3].w;
    res.w = (s01 + s23) + bias[e_base + 3];
    *(float4*)(lg + (size_t)(rowBase + lane) * NE + e_base) = res;
  }
}

// B: per-row softmax + top-8 + dense scatter, logits read+overwritten in place.
__global__ __launch_bounds__(256, 1)
void finish_kernel(float* __restrict__ gate, float* __restrict__ out_vals,
                   float* __restrict__ out_idx)
{
  const int r = blockIdx.x * 256 + threadIdx.x;
  float l[NE], p[NE];
  {
    const float4* gp = (const float4*)(gate + (size_t)r * NE);
    float4* lp = (float4*)l;
#pragma unroll
    for (int i = 0; i < 16; ++i) lp[i] = gp[i];
  }
  float m = l[0];
#pragma unroll
  for (int e = 1; e < NE; ++e) m = fmaxf(m, l[e]);
#pragma unroll
  for (int e = 0; e < NE; ++e) p[e] = expf(l[e] - m);
  float rs[8];
#pragma unroll
  for (int j = 0; j < 8; ++j) rs[j] = p[j];
#pragma unroll
  for (int i = 8; i < NE; i += 8)
#pragma unroll
    for (int j = 0; j < 8; ++j) rs[j] = rs[j] + p[i + j];
  float s = ((rs[0] + rs[1]) + (rs[2] + rs[3])) + ((rs[4] + rs[5]) + (rs[6] + rs[7]));
#pragma unroll
  for (int e = 0; e < NE; ++e) p[e] = p[e] / s;

  // top-8 ranked by exact logits (r3-passed semantics): strict >, low idx tie.
  unsigned long long used = 0;
#pragma unroll
  for (int k = 0; k < 8; ++k) {
    float best = -INFINITY; int bi = 0;
#pragma unroll
    for (int e = 0; e < NE; ++e) {
      bool ok = (((used >> e) & 1ull) == 0ull) && (l[e] > best);
      best = ok ? l[e] : best;
      bi   = ok ? e    : bi;
    }
    used |= 1ull << bi;
    out_vals[(size_t)r * 8 + k] = p[bi];
    out_idx [(size_t)r * 8 + k] = (float)bi;
  }

  {
    float4* gp = (float4*)(gate + (size_t)r * NE);
#pragma unroll
    for (int i = 0; i < 16; ++i) {
      int e = i << 2;
      float4 v;
      v.x = ((used >> (e + 0)) & 1ull) ? p[e + 0] : 0.0f;
      v.y = ((used >> (e + 1)) & 1ull) ? p[e + 1] : 0.0f;
      v.z = ((used >> (e + 2)) & 1ull) ? p[e + 2] : 0.0f;
      v.w = ((used >> (e + 3)) & 1ull) ? p[e + 3] : 0.0f;
      gp[i] = v;
    }
  }
}

extern "C" void kernel_launch(void* const* d_in, const int* in_sizes, int n_in,
                              void* d_out, int out_size, void* d_ws, size_t ws_size,
                              hipStream_t stream) {
  const float* x    = (const float*)d_in[0];
  const float* w    = (const float*)d_in[1];
  const float* bias = (const float*)d_in[2];
  float* out   = (float*)d_out;
  float* vals  = out;                       // 16384*8
  float* idx   = out + (size_t)NROWS * 8;   // 16384*8
  float* dense = out + (size_t)NROWS * 16;  // 16384*64 (A's logit scratch)
  (void)in_sizes; (void)n_in; (void)out_size; (void)d_ws; (void)ws_size;
  logits_kernel<<<dim3(1024), dim3(256), 0, stream>>>(x, w, bias, dense);
  finish_kernel<<<dim3(NROWS / 256), dim3(256), 0, stream>>>(dense, vals, idx);
}

// Round 6
// 337.953 us; speedup vs baseline: 2.5089x; 1.1037x over previous
//
#include <hip/hip_runtime.h>
#include <math.h>

// Unfused mul/add EVERYWHERE (file scope): the exact-chain replication of
// numpy's einsum requires separately-rounded mul and add.
#pragma clang fp contract(off)

// MoE gate: logits = x @ W^T + bias ; softmax ; top-8 ; dense scatter.
// Outputs (float32): vals[16384*8] | idx[16384*8] | dense[16384*64].
//
// PASSED math (r3/r5) — DO NOT CHANGE: logits replicate numpy's einsum inner
// loop (npyv SSE2/SSE3, no FMA): 16-element blocks ascending, REVERSE vector
// order within block, every mul/add separately rounded, final SSE3 hadd tree
// (L0+L1)+(L2+L3). Top-8 ranked by these exact f32 logits, strict >, lowest
// index on tie; softmax = exp(l-max), np pairwise-8 sum, IEEE div.
//
// r6: same structure as r5 (1024 blocks x 256 thr, 64 rows x 16 experts,
// global_load_lds x-staging + XOR swizzle, counted vmcnt) but compute() is
// explicitly software-pipelined: all 16 x ds_reads hoisted to tile start,
// W prefetched 3 (b,e)-steps ahead into a 4-slot rotating register file.
// r5 stalled ~65% on per-(b,e) W s_load latency (lgkmcnt drain every 64cy
// of math); this hides it.

#define NROWS 16384
#define DIM   2048
#define NE    64
#define DC    64
#define NTILES (DIM / DC)   // 32

__device__ __forceinline__ void ld16_lds(const float* g, void* l) {
  __builtin_amdgcn_global_load_lds((const __attribute__((address_space(1))) void*)g,
                                   (__attribute__((address_space(3))) void*)l, 16, 0, 0);
}

// np 16-element block, reverse order, unfused mul/add.
#define NP_BLOCK(A, Q0, Q1, Q2, Q3, R0, R1, R2, R3) \
  A.x = A.x + Q3.x * R3.x;  A.y = A.y + Q3.y * R3.y; \
  A.z = A.z + Q3.z * R3.z;  A.w = A.w + Q3.w * R3.w; \
  A.x = A.x + Q2.x * R2.x;  A.y = A.y + Q2.y * R2.y; \
  A.z = A.z + Q2.z * R2.z;  A.w = A.w + Q2.w * R2.w; \
  A.x = A.x + Q1.x * R1.x;  A.y = A.y + Q1.y * R1.y; \
  A.z = A.z + Q1.z * R1.z;  A.w = A.w + Q1.w * R1.w; \
  A.x = A.x + Q0.x * R0.x;  A.y = A.y + Q0.y * R0.y; \
  A.z = A.z + Q0.z * R0.z;  A.w = A.w + Q0.w * R0.w;

__global__ __launch_bounds__(256, 4)
void logits_kernel(const float* __restrict__ x, const float* __restrict__ w,
                   const float* __restrict__ bias, float* __restrict__ lg)
{
  __shared__ float4 xs[2][64 * (DC / 4)];   // 2 x 16 KB

  const int t    = threadIdx.x;
  const int wv   = t >> 6;      // 0..3 -> expert quad within group
  const int lane = t & 63;      // row within tile
  // XCD decode: 4 sibling blocks (same 64 rows, expert groups 0..3) share an
  // XCD so the x-tile is fetched once per XCD L2 (default assignment = bid&7).
  const int bid = blockIdx.x;          // 0..1023
  const int ix  = bid >> 3;            // 0..127
  const int qg  = ix & 3;              // expert group
  const int rg  = (bid & 7) + ((ix >> 2) << 3);  // row group 0..255 (bijective)
  const int rowBase = rg << 6;
  const int e_base  = __builtin_amdgcn_readfirstlane((qg << 4) | (wv << 2));
  const float* wb = w + (size_t)e_base * DIM;   // wave-uniform -> s_load path

  auto stage = [&](int buf, int kt) {
    const int d0 = kt * DC;
#pragma unroll
    for (int it = 0; it < 4; ++it) {
      int q   = (it << 8) + t;     // float4 index in [64][16] tile
      int row = q >> 4;
      int sp  = q & 15;
      int ss  = sp ^ (row & 7);    // swizzle on the GLOBAL source (involution)
      const float* g = x + (size_t)(rowBase + row) * DIM + d0 + (ss << 2);
      ld16_lds(g, &xs[buf][q]);
    }
  };

  float4 acc[4];
#pragma unroll
  for (int e = 0; e < 4; ++e) acc[e] = make_float4(0.f, 0.f, 0.f, 0.f);

  // W load for flattened step K (b = K>>2, e = K&3) into rotating slot K&3.
  // All indices compile-time constants after full unroll (no scratch).
#define LOADW(K) do {                                              \
    const int _b = (K) >> 2, _e = (K) & 3;                         \
    const float* _p = wt + (size_t)_e * DIM + (_b << 4);           \
    wsl[(K) & 3][0] = *(const float4*)(_p);                        \
    wsl[(K) & 3][1] = *(const float4*)(_p + 4);                    \
    wsl[(K) & 3][2] = *(const float4*)(_p + 8);                    \
    wsl[(K) & 3][3] = *(const float4*)(_p + 12);                   \
  } while (0)

  auto compute = [&](int buf, const float* wt) {
    const float4* xr = &xs[buf][lane << 4];
    const int sw = lane & 7;
    // hoist the whole x tile (16 float4 = 64 VGPR); counted lgkm covers it
    float4 q[4][4];
#pragma unroll
    for (int b = 0; b < 4; ++b)
#pragma unroll
      for (int j = 0; j < 4; ++j) q[b][j] = xr[(4 * b + j) ^ sw];

    float4 wsl[4][4];
    LOADW(0); LOADW(1); LOADW(2);          // prime 3 slots
#pragma unroll
    for (int i = 0; i < 16; ++i) {         // i = b*4 + e; b outer asc, e inner
      if (i + 3 < 16) LOADW(i + 3);        // prefetch distance 3
      const int b = i >> 2, e = i & 3;
      NP_BLOCK(acc[e], q[b][0], q[b][1], q[b][2], q[b][3],
               wsl[i & 3][0], wsl[i & 3][1], wsl[i & 3][2], wsl[i & 3][3]);
    }
  };

  stage(0, 0);
#pragma unroll 1
  for (int kt = 0; kt < NTILES - 1; ++kt) {
    stage((kt + 1) & 1, kt + 1);                       // prefetch next tile
    asm volatile("s_waitcnt vmcnt(4)" ::: "memory");   // cur tile staged
    __builtin_amdgcn_s_barrier();
    compute(kt & 1, wb + kt * DC);
    __builtin_amdgcn_s_barrier();                      // readers done
    asm volatile("" ::: "memory");
  }
  asm volatile("s_waitcnt vmcnt(0)" ::: "memory");
  __builtin_amdgcn_s_barrier();
  compute((NTILES - 1) & 1, wb + (NTILES - 1) * DC);

  {
    float4 res;
    float s01, s23;
    s01 = acc[0].x + acc[0].y; s23 = acc[0].z + acc[0].w;
    res.x = (s01 + s23) + bias[e_base + 0];
    s01 = acc[1].x + acc[1].y; s23 = acc[1].z + acc[1].w;
    res.y = (s01 + s23) + bias[e_base + 1];
    s01 = acc[2].x + acc[2].y; s23 = acc[2].z + acc[2].w;
    res.z = (s01 + s23) + bias[e_base + 2];
    s01 = acc[3].x + acc[3].y; s23 = acc[3].z + acc[3].w;
    res.w = (s01 + s23) + bias[e_base + 3];
    *(float4*)(lg + (size_t)(rowBase + lane) * NE + e_base) = res;
  }
}

// B: per-row softmax + top-8 + dense scatter, logits read+overwritten in place.
__global__ __launch_bounds__(256, 1)
void finish_kernel(float* __restrict__ gate, float* __restrict__ out_vals,
                   float* __restrict__ out_idx)
{
  const int r = blockIdx.x * 256 + threadIdx.x;
  float l[NE], p[NE];
  {
    const float4* gp = (const float4*)(gate + (size_t)r * NE);
    float4* lp = (float4*)l;
#pragma unroll
    for (int i = 0; i < 16; ++i) lp[i] = gp[i];
  }
  float m = l[0];
#pragma unroll
  for (int e = 1; e < NE; ++e) m = fmaxf(m, l[e]);
#pragma unroll
  for (int e = 0; e < NE; ++e) p[e] = expf(l[e] - m);
  float rs[8];
#pragma unroll
  for (int j = 0; j < 8; ++j) rs[j] = p[j];
#pragma unroll
  for (int i = 8; i < NE; i += 8)
#pragma unroll
    for (int j = 0; j < 8; ++j) rs[j] = rs[j] + p[i + j];
  float s = ((rs[0] + rs[1]) + (rs[2] + rs[3])) + ((rs[4] + rs[5]) + (rs[6] + rs[7]));
#pragma unroll
  for (int e = 0; e < NE; ++e) p[e] = p[e] / s;

  // top-8 ranked by exact logits (r3-passed semantics): strict >, low idx tie.
  unsigned long long used = 0;
#pragma unroll
  for (int k = 0; k < 8; ++k) {
    float best = -INFINITY; int bi = 0;
#pragma unroll
    for (int e = 0; e < NE; ++e) {
      bool ok = (((used >> e) & 1ull) == 0ull) && (l[e] > best);
      best = ok ? l[e] : best;
      bi   = ok ? e    : bi;
    }
    used |= 1ull << bi;
    out_vals[(size_t)r * 8 + k] = p[bi];
    out_idx [(size_t)r * 8 + k] = (float)bi;
  }

  {
    float4* gp = (float4*)(gate + (size_t)r * NE);
#pragma unroll
    for (int i = 0; i < 16; ++i) {
      int e = i << 2;
      float4 v;
      v.x = ((used >> (e + 0)) & 1ull) ? p[e + 0] : 0.0f;
      v.y = ((used >> (e + 1)) & 1ull) ? p[e + 1] : 0.0f;
      v.z = ((used >> (e + 2)) & 1ull) ? p[e + 2] : 0.0f;
      v.w = ((used >> (e + 3)) & 1ull) ? p[e + 3] : 0.0f;
      gp[i] = v;
    }
  }
}

extern "C" void kernel_launch(void* const* d_in, const int* in_sizes, int n_in,
                              void* d_out, int out_size, void* d_ws, size_t ws_size,
                              hipStream_t stream) {
  const float* x    = (const float*)d_in[0];
  const float* w    = (const float*)d_in[1];
  const float* bias = (const float*)d_in[2];
  float* out   = (float*)d_out;
  float* vals  = out;                       // 16384*8
  float* idx   = out + (size_t)NROWS * 8;   // 16384*8
  float* dense = out + (size_t)NROWS * 16;  // 16384*64 (A's logit scratch)
  (void)in_sizes; (void)n_in; (void)out_size; (void)d_ws; (void)ws_size;
  logits_kernel<<<dim3(1024), dim3(256), 0, stream>>>(x, w, bias, dense);
  finish_kernel<<<dim3(NROWS / 256), dim3(256), 0, stream>>>(dense, vals, idx);
}